// Round 3
// baseline (302.267 us; speedup 1.0000x reference)
//
#include <hip/hip_runtime.h>

// TokenMixer: out[n,b,c] = x_pos[n,b,c] * (1 - sigmoid(cos_sim(x_pre[n,b,:], x_pos[n,b,:])))
// N=4096, B=16, C=512 -> 65536 rows of 512 elements.
// Inputs: float32. Output: float32 (reference output dtype).
// One wave (64 lanes) per row; each lane owns 8 contiguous fp32 (two float4
// loads per tensor), fp32 butterfly reduce, two float4 stores.

constexpr int C_DIM = 512;
constexpr int ROWS  = 4096 * 16;   // 65536

__global__ __launch_bounds__(256) void tokenmixer_kernel(
    const float* __restrict__ pre,
    const float* __restrict__ pos,
    float* __restrict__ out)
{
    const int row  = (int)((blockIdx.x * 256u + threadIdx.x) >> 6);
    const int lane = (int)(threadIdx.x & 63u);
    const size_t base = (size_t)row * C_DIM + (size_t)lane * 8;

    // 8 contiguous fp32 per lane per tensor
    const float4 p0 = *reinterpret_cast<const float4*>(pre + base);
    const float4 p1 = *reinterpret_cast<const float4*>(pre + base + 4);
    const float4 q0 = *reinterpret_cast<const float4*>(pos + base);
    const float4 q1 = *reinterpret_cast<const float4*>(pos + base + 4);

    float pf[8] = {p0.x, p0.y, p0.z, p0.w, p1.x, p1.y, p1.z, p1.w};
    float qf[8] = {q0.x, q0.y, q0.z, q0.w, q1.x, q1.y, q1.z, q1.w};

    float s_pre = 0.f, s_pos = 0.f, dot = 0.f;
#pragma unroll
    for (int i = 0; i < 8; ++i) {
        s_pre = fmaf(pf[i], pf[i], s_pre);
        s_pos = fmaf(qf[i], qf[i], s_pos);
        dot   = fmaf(pf[i], qf[i], dot);
    }

    // 64-lane butterfly reduction
#pragma unroll
    for (int m = 1; m < 64; m <<= 1) {
        s_pre += __shfl_xor(s_pre, m, 64);
        s_pos += __shfl_xor(s_pos, m, 64);
        dot   += __shfl_xor(dot,   m, 64);
    }

    const float n_pre = fmaxf(sqrtf(s_pre), 1e-12f);
    const float n_pos = fmaxf(sqrtf(s_pos), 1e-12f);
    const float cosv  = dot / (n_pre * n_pos);
    // 1 - sigmoid(x) = 1 / (1 + e^x)
    const float w = 1.0f / (1.0f + __expf(cosv));

    float4 o0, o1;
    o0.x = qf[0] * w; o0.y = qf[1] * w; o0.z = qf[2] * w; o0.w = qf[3] * w;
    o1.x = qf[4] * w; o1.y = qf[5] * w; o1.z = qf[6] * w; o1.w = qf[7] * w;
    *reinterpret_cast<float4*>(out + base)     = o0;
    *reinterpret_cast<float4*>(out + base + 4) = o1;
}

extern "C" void kernel_launch(void* const* d_in, const int* in_sizes, int n_in,
                              void* d_out, int out_size, void* d_ws, size_t ws_size,
                              hipStream_t stream) {
    const float* pre = (const float*)d_in[0];
    const float* pos = (const float*)d_in[1];
    float* out = (float*)d_out;

    // 4 rows per 256-thread block
    const int blocks = ROWS / 4;  // 16384
    tokenmixer_kernel<<<blocks, 256, 0, stream>>>(pre, pos, out);
}